// Round 2
// baseline (534.780 us; speedup 1.0000x reference)
//
#include <hip/hip_runtime.h>
#include <hip/hip_bf16.h>
#include <math.h>

// Problem constants (fixed by the reference)
#define Bsz   8
#define LQ    9216
#define DIM   384
#define NH    6
#define NPTS  4
#define HD    64
#define H0    96
#define W0    96
#define NROWS (Bsz * LQ)        // 73728
#define LN_EPS 1e-5f

typedef __attribute__((ext_vector_type(8))) short short8;   // 8 bf16 = 4 VGPRs
typedef __attribute__((ext_vector_type(4))) float f32x4;

__device__ __forceinline__ void load_lds16(const void* g, void* l) {
    __builtin_amdgcn_global_load_lds(
        (const __attribute__((address_space(1))) void*)g,
        (__attribute__((address_space(3))) void*)l,
        16, 0, 0);
}

__device__ __forceinline__ float bf_lo(unsigned u) { return __uint_as_float(u << 16); }
__device__ __forceinline__ float bf_hi(unsigned u) { return __uint_as_float(u & 0xffff0000u); }

// ---------------------------------------------------------------------------
// Kernel 1: fused LayerNorm -> bf16.  One wave per row, 4 rows/block.
// ---------------------------------------------------------------------------
__global__ __launch_bounds__(256) void lnorm_kernel(
    const float* __restrict__ X,
    const float* __restrict__ w, const float* __restrict__ bvec,
    __hip_bfloat16* __restrict__ Y)
{
    int wave = threadIdx.x >> 6, lane = threadIdx.x & 63;
    int row = blockIdx.x * 4 + wave;
    const float* x = X + (size_t)row * DIM;
    float2 v[3];
    float s = 0.f, sq = 0.f;
#pragma unroll
    for (int i = 0; i < 3; ++i) {
        v[i] = *(const float2*)&x[lane * 2 + i * 128];
        s  += v[i].x + v[i].y;
        sq += v[i].x * v[i].x + v[i].y * v[i].y;
    }
#pragma unroll
    for (int off = 1; off < 64; off <<= 1) {
        s  += __shfl_xor(s,  off, 64);
        sq += __shfl_xor(sq, off, 64);
    }
    float mu   = s * (1.f / DIM);
    float rstd = rsqrtf(sq * (1.f / DIM) - mu * mu + LN_EPS);
#pragma unroll
    for (int i = 0; i < 3; ++i) {
        int p = lane * 2 + i * 128;
        float2 ww = *(const float2*)&w[p];
        float2 bb = *(const float2*)&bvec[p];
        __hip_bfloat162 o;
        o.x = __float2bfloat16((v[i].x - mu) * rstd * ww.x + bb.x);
        o.y = __float2bfloat16((v[i].y - mu) * rstd * ww.y + bb.y);
        *(__hip_bfloat162*)&Y[(size_t)row * DIM + p] = o;
    }
}

// ---------------------------------------------------------------------------
// Kernel 2: weight transpose + cvt to bf16 [N][K] layout (one-shot, tiny).
// ---------------------------------------------------------------------------
__global__ __launch_bounds__(256) void wtrans_kernel(
    const float* __restrict__ wv, const float* __restrict__ wo,
    const float* __restrict__ woff, const float* __restrict__ watt,
    __hip_bfloat16* __restrict__ WtV, __hip_bfloat16* __restrict__ WtO,
    __hip_bfloat16* __restrict__ WtS)
{
    int gid = blockIdx.x * 256 + threadIdx.x;
    if (gid < 147456) {
        int n = gid / 384, k = gid % 384;
        WtV[gid] = __float2bfloat16(wv[k * 384 + n]);
    } else if (gid < 294912) {
        int i = gid - 147456;
        int n = i / 384, k = i % 384;
        WtO[i] = __float2bfloat16(wo[k * 384 + n]);
    } else {
        int i = gid - 294912;
        int n = i / 384, k = i % 384;
        float v = 0.f;
        if (n < 48)      v = woff[k * 48 + n];
        else if (n < 72) v = watt[k * 24 + (n - 48)];
        WtS[i] = __float2bfloat16(v);
    }
}

// ---------------------------------------------------------------------------
// Kernel 3: bf16 MFMA GEMM (m97 structure): C = A @ Bt^T (+epilogue)
//   Grid: (col_panels, row_panels) — col-panel is the FAST dispatch dim so
//   the 3 blocks sharing one A row-panel are consecutive -> A served from L2.
//   MODE 0: value GEMM  -> bf16 store, transposed layout (b,h,pix,64)
//   MODE 1: final GEMM  -> fp32 store, out = resid + gamma*(acc+bias)
//   MODE 2: off+attn    -> cols 0..47 -> offbuf, 48..71 -> attbuf (fp32)
// ---------------------------------------------------------------------------
template<int MODE>
__global__ __launch_bounds__(256) void gemm16_kernel(
    const __hip_bfloat16* __restrict__ A,
    const __hip_bfloat16* __restrict__ Bt,
    const float* __restrict__ bias,
    const float* __restrict__ bias2,
    const float* __restrict__ resid,
    const float* __restrict__ gamma,
    void* __restrict__ out0,
    void* __restrict__ out1)
{
    __shared__ short As[128 * 32];
    __shared__ short Bs[128 * 32];

    const int t    = threadIdx.x;
    const int lane = t & 63;
    const int w    = t >> 6;
    const int wm   = w >> 1, wn = w & 1;
    const int row0 = blockIdx.y * 128;
    const int col0 = blockIdx.x * 128;
    const int lm   = lane & 15, lq = lane >> 4;

    f32x4 acc[4][4];
#pragma unroll
    for (int i = 0; i < 4; ++i)
#pragma unroll
        for (int j = 0; j < 4; ++j)
            acc[i][j] = (f32x4){0.f, 0.f, 0.f, 0.f};

    for (int k0 = 0; k0 < 384; k0 += 32) {
#pragma unroll
        for (int j = 0; j < 2; ++j) {
            int seg = w * 2 + j;                 // 0..7, 16 rows each
            int rr  = seg * 16 + (lane >> 2);
            const char* gA = (const char*)(A  + ((size_t)(row0 + rr) * 384 + k0)) + (lane & 3) * 16;
            const char* gB = (const char*)(Bt + ((size_t)(col0 + rr) * 384 + k0)) + (lane & 3) * 16;
            load_lds16(gA, (char*)As + seg * 1024);
            load_lds16(gB, (char*)Bs + seg * 1024);
        }
        __syncthreads();

        short8 af[4], bf[4];
#pragma unroll
        for (int i = 0; i < 4; ++i) {
            af[i] = *(const short8*)&As[(wm * 64 + i * 16 + lm) * 32 + lq * 8];
            bf[i] = *(const short8*)&Bs[(wn * 64 + i * 16 + lm) * 32 + lq * 8];
        }
#pragma unroll
        for (int i = 0; i < 4; ++i)
#pragma unroll
            for (int j = 0; j < 4; ++j)
                acc[i][j] = __builtin_amdgcn_mfma_f32_16x16x32_bf16(af[i], bf[j], acc[i][j], 0, 0, 0);
        __syncthreads();
    }

#pragma unroll
    for (int i = 0; i < 4; ++i) {
#pragma unroll
        for (int j = 0; j < 4; ++j) {
            const int col = col0 + wn * 64 + j * 16 + lm;
#pragma unroll
            for (int r = 0; r < 4; ++r) {
                const int row = row0 + wm * 64 + i * 16 + lq * 4 + r;
                float v = acc[i][j][r];
                if (MODE == 0) {
                    v += bias[col];
                    int b = row / LQ, pix = row - b * LQ;
                    int h = col >> 6, d = col & 63;
                    ((__hip_bfloat16*)out0)[(((size_t)(b * NH + h)) * LQ + pix) * 64 + d] =
                        __float2bfloat16(v);
                } else if (MODE == 1) {
                    v += bias[col];
                    size_t o = (size_t)row * 384 + col;
                    ((float*)out0)[o] = resid[o] + gamma[col] * v;
                } else {
                    if (col < 48)
                        ((float*)out0)[(size_t)row * 48 + col] = v + bias[col];
                    else if (col < 72)
                        ((float*)out1)[(size_t)row * 24 + (col - 48)] = v + bias2[col - 48];
                }
            }
        }
    }
}

// ---------------------------------------------------------------------------
// Kernel 4: loc transform + softmax -> packed task-major sample table.
//   smp[((bh*LQ)+q)*4 + p] = {x_scaled, y_scaled, attw, 0}
// ---------------------------------------------------------------------------
__global__ __launch_bounds__(256) void locsoftmax_kernel(
    const float* __restrict__ offbuf, const float* __restrict__ attbuf,
    const float* __restrict__ refpts, float4* __restrict__ smp)
{
    int gid = blockIdx.x * blockDim.x + threadIdx.x;
    int row = gid / NH;
    int h   = gid % NH;
    int b   = row / LQ, q = row - b * LQ;
    size_t task = (size_t)(b * NH + h) * LQ + q;

    const float rx = refpts[row * 2 + 0];
    const float ry = refpts[row * 2 + 1];

    const float* off = offbuf + (size_t)row * (NH * NPTS * 2) + h * (NPTS * 2);
    const float* att = attbuf + (size_t)row * (NH * NPTS)     + h * NPTS;

    float l0 = att[0], l1 = att[1], l2 = att[2], l3 = att[3];
    float m  = fmaxf(fmaxf(l0, l1), fmaxf(l2, l3));
    float e[4] = {expf(l0 - m), expf(l1 - m), expf(l2 - m), expf(l3 - m)};
    float inv = 1.f / (e[0] + e[1] + e[2] + e[3]);

#pragma unroll
    for (int p = 0; p < NPTS; ++p) {
        float x = (rx + off[p * 2 + 0] * (1.f / W0)) * (float)W0 - 0.5f;
        float y = (ry + off[p * 2 + 1] * (1.f / H0)) * (float)H0 - 0.5f;
        smp[task * 4 + p] = make_float4(x, y, e[p] * inv, 0.f);
    }
}

// ---------------------------------------------------------------------------
// Kernel 5: deformable sampling, 4 tasks per wave.
//   lane = slot*16 + c4 ; slot = which of 4 consecutive q (same b,h plane);
//   c4 = channel group (4 bf16 = 8 B per tap-load). Clamp-index +
//   zero-weight for OOB (matches reference clip+mask semantics).
// ---------------------------------------------------------------------------
__global__ __launch_bounds__(256) void sample_kernel(
    const __hip_bfloat16* __restrict__ vt,   // (bh, pix, 64) bf16
    const float4* __restrict__ smp,          // (task, 4) {x,y,w,_}
    __hip_bfloat16* __restrict__ out)        // (row, 384) bf16
{
    const int wave = threadIdx.x >> 6, lane = threadIdx.x & 63;
    const int slot = lane >> 4;
    const int c4   = lane & 15;
    const int task = (blockIdx.x * 4 + wave) * 4 + slot;
    const int bh   = task / LQ;              // wave-uniform (LQ % 4 == 0)
    const int q    = task - bh * LQ;
    const int b    = bh / NH, h = bh - b * NH;

    const __hip_bfloat16* vbase = vt + (size_t)bh * LQ * 64;   // uniform base

    float a0 = 0.f, a1 = 0.f, a2 = 0.f, a3 = 0.f;

#pragma unroll
    for (int p = 0; p < NPTS; ++p) {
        float4 s = smp[(size_t)task * 4 + p];
        float x = s.x, y = s.y, wgt = s.z;
        float xf = floorf(x), yf = floorf(y);
        int   x0 = (int)xf,   y0 = (int)yf;
        float fx = x - xf,    fy = y - yf;
        float gx0 = 1.f - fx, gx1 = fx;
        float gy0w = (1.f - fy) * wgt, gy1w = fy * wgt;

#pragma unroll
        for (int cy = 0; cy < 2; ++cy) {
            const int   yi = y0 + cy;
            const float wy = cy ? gy1w : gy0w;
            const bool  vy = (unsigned)yi < H0;
            const int   yc = min(max(yi, 0), H0 - 1);
#pragma unroll
            for (int cx = 0; cx < 2; ++cx) {
                const int xi = x0 + cx;
                float wc = wy * (cx ? gx1 : gx0);
                if (!vy || (unsigned)xi >= W0) wc = 0.f;
                const int xc = min(max(xi, 0), W0 - 1);
                const uint2 raw = *(const uint2*)(vbase + (size_t)(yc * W0 + xc) * 64 + c4 * 4);
                a0 = fmaf(wc, bf_lo(raw.x), a0);
                a1 = fmaf(wc, bf_hi(raw.x), a1);
                a2 = fmaf(wc, bf_lo(raw.y), a2);
                a3 = fmaf(wc, bf_hi(raw.y), a3);
            }
        }
    }

    const int row = b * LQ + q;
    __hip_bfloat162 o01, o23;
    o01.x = __float2bfloat16(a0); o01.y = __float2bfloat16(a1);
    o23.x = __float2bfloat16(a2); o23.y = __float2bfloat16(a3);
    __hip_bfloat162* op = (__hip_bfloat162*)(out + (size_t)row * DIM + h * HD + c4 * 4);
    op[0] = o01;
    op[1] = o23;
}

// ---------------------------------------------------------------------------
// Launch
// ---------------------------------------------------------------------------
extern "C" void kernel_launch(void* const* d_in, const int* in_sizes, int n_in,
                              void* d_out, int out_size, void* d_ws, size_t ws_size,
                              hipStream_t stream)
{
    const float* query   = (const float*)d_in[0];
    const float* refpts  = (const float*)d_in[1];
    const float* feat    = (const float*)d_in[2];
    const float* qn_w    = (const float*)d_in[5];
    const float* qn_b    = (const float*)d_in[6];
    const float* fn_w    = (const float*)d_in[7];
    const float* fn_b    = (const float*)d_in[8];
    const float* w_value = (const float*)d_in[9];
    const float* b_value = (const float*)d_in[10];
    const float* w_off   = (const float*)d_in[11];
    const float* b_off   = (const float*)d_in[12];
    const float* w_attn  = (const float*)d_in[13];
    const float* b_attn  = (const float*)d_in[14];
    const float* w_out   = (const float*)d_in[15];
    const float* b_out   = (const float*)d_in[16];
    const float* gamma   = (const float*)d_in[17];

    char* wsb = (char*)d_ws;
    __hip_bfloat16* Q16    = (__hip_bfloat16*)wsb;                 // 56.6 MB
    __hip_bfloat16* F16    = (__hip_bfloat16*)(wsb + 56623104);    // 56.6 MB
    __hip_bfloat16* vtrans = (__hip_bfloat16*)(wsb + 113246208);   // 56.6 MB
    __hip_bfloat16* att16  = (__hip_bfloat16*)(wsb + 169869312);   // 56.6 MB
    float*          offbuf = (float*)(wsb + 226492416);            // 14.2 MB
    float*          attbuf = (float*)(wsb + 240648192);            // 7.1 MB
    __hip_bfloat16* WtV    = (__hip_bfloat16*)(wsb + 247726080);   // 294912 B
    __hip_bfloat16* WtO    = (__hip_bfloat16*)(wsb + 248020992);   // 294912 B
    __hip_bfloat16* WtS    = (__hip_bfloat16*)(wsb + 248315904);   // 98304 B
    float4*         smp    = (float4*)wsb;  // aliases Q16 (dead after MODE2 GEMM)
    float* outp = (float*)d_out;

    // 1-2. LayerNorms -> bf16
    lnorm_kernel<<<NROWS / 4, 256, 0, stream>>>(query, qn_w, qn_b, Q16);
    lnorm_kernel<<<NROWS / 4, 256, 0, stream>>>(feat,  fn_w, fn_b, F16);

    // 3. weight transpose/cvt
    wtrans_kernel<<<1344, 256, 0, stream>>>(w_value, w_out, w_off, w_attn,
                                            WtV, WtO, WtS);

    // 4. value = LN(feat) @ w_value + b_value  -> bf16 (b,h,pix,64) layout
    gemm16_kernel<0><<<dim3(3, NROWS / 128), 256, 0, stream>>>(
        F16, WtV, b_value, nullptr, nullptr, nullptr, vtrans, nullptr);

    // 5. off/attn logits = LN(q) @ [w_off|w_attn]  (one 128-col MFMA GEMM)
    gemm16_kernel<2><<<dim3(1, NROWS / 128), 256, 0, stream>>>(
        Q16, WtS, b_off, b_attn, nullptr, nullptr, offbuf, attbuf);

    // 6. sample coords + softmax -> packed task-major table (over dead Q16)
    locsoftmax_kernel<<<(NROWS * NH) / 256, 256, 0, stream>>>(
        offbuf, attbuf, refpts, smp);

    // 7. deformable bilinear sampling, 4 tasks/wave -> bf16 attn_out
    sample_kernel<<<(NROWS * NH) / 16, 256, 0, stream>>>(
        vtrans, smp, att16);

    // 8. out = query + gamma * (attn_out @ w_out + b_out)
    gemm16_kernel<1><<<dim3(3, NROWS / 128), 256, 0, stream>>>(
        att16, WtO, b_out, nullptr, query, gamma, outp, nullptr);
}